// Round 10
// baseline (396.852 us; speedup 1.0000x reference)
//
#include <hip/hip_runtime.h>
#include <stdint.h>

// Problem constants (B=8, S=8192, D_IN=512, D=512)
#define Bb   8
#define Ss   8192
#define DIN  512
#define Dd   512
#define M_TOT (Bb * Ss)      // 65536 rows
#define NC   64              // chunks along S
#define CL   128             // chunk length (NC*CL == Ss) == GEMM M-tile

// ws layout (bytes)
static const size_t CV_OFF  = 0;                          // bf16x2 [65536][512] = 128 MiB
static const size_t WT_OFF  = 134217728ull;               // bf16 [1024][512]   =   1 MiB
static const size_t AG_OFF  = WT_OFF + 1048576ull;        // float2[512][512]   =   2 MiB
static const size_t WS_NEED = AG_OFF + 2097152ull;        // ~131 MiB total

typedef short  short8 __attribute__((ext_vector_type(8)));
typedef float  f32x4  __attribute__((ext_vector_type(4)));

__device__ __forceinline__ unsigned short bf16_rne(float f) {
  uint32_t u = __float_as_uint(f);
  u += 0x7fffu + ((u >> 16) & 1u);
  return (unsigned short)(u >> 16);
}

__device__ __forceinline__ void gload16(const unsigned short* g, void* l) {
  __builtin_amdgcn_global_load_lds(
      (const __attribute__((address_space(1))) uint32_t*)g,
      (__attribute__((address_space(3))) uint32_t*)l, 16, 0, 0);
}

__device__ __forceinline__ uint32_t cvt_pk_bf16(float lo, float hi) {
  uint32_t r;
  asm("v_cvt_pk_bf16_f32 %0, %1, %2" : "=v"(r) : "v"(lo), "v"(hi));
  return r;
}

// ---------------------------------------------------------------------------
// Pre-pass: W -> wt bf16 [1024 n'][512 k]   (x is consumed f32 by the GEMM)
//   n' interleave (16-granular): hidden col d -> n'=32*(d>>4)+(d&15),
//                                gate   col d -> n'=32*(d>>4)+16+(d&15)
// ---------------------------------------------------------------------------
__global__ void k_prep_wt(const float* __restrict__ W, unsigned short* __restrict__ wt) {
  for (int i = blockIdx.x * 256 + threadIdx.x; i < 512 * 1024; i += 512 * 256) {
    int k = i >> 10;       // W row
    int j = i & 1023;      // W col
    float w = W[i];
    int n = (j < 512) ? (32 * (j >> 4) + (j & 15))
                      : (32 * ((j - 512) >> 4) + 16 + ((j - 512) & 15));
    wt[n * 512 + k] = bf16_rne(w);
  }
}

// ---------------------------------------------------------------------------
// GEMM: (65536 x 512) * (512 x 1024) -> fused pointwise -> cv bf16x2
//       + fused per-chunk scan aggregates (M-tile IS one 128-row chunk)
// 128x128 tile, BK=32, 4 waves (2x2 of 64x64), 16x16x32 bf16 MFMA.
// A staged DIRECTLY from f32 x: reg-load (issued before COMPUTE) -> cvt_pk
// -> ds_write_b128 to the SAME linear dest gload_lds used (rule 21 kept:
// source chunk swizzle s^((r>>1)&3) unchanged, read slot q^((r>>1)&3)).
// B staged via global_load_lds from bf16 wt. One barrier per K-step.
// XCD-aware mapping: 8 nb-blocks sharing an A-panel land on the SAME XCD.
// ---------------------------------------------------------------------------
__global__ void __launch_bounds__(256) k_gemm(const float* __restrict__ x,
                                              const unsigned short* __restrict__ wt,
                                              uint32_t* __restrict__ cvu,
                                              float2* __restrict__ agg) {
  __shared__ __align__(16) unsigned short As[2][128 * 32];
  __shared__ __align__(16) unsigned short Bsh[2][128 * 32];
  __shared__ float aggC[2][2][2][16];   // [wr][wc][t][lane&15]
  __shared__ float aggV[2][2][2][16];

  const int tid  = threadIdx.x;
  const int lane = tid & 63;
  const int wave = tid >> 6;
  const int wr = wave >> 1, wc = wave & 1;

  // XCD-aware tile mapping (round-robin bid%8 -> XCD assumed)
  const int bid = blockIdx.x;
  const int xcd = bid & 7;
  const int j8  = bid >> 3;              // 0..511, sequential per XCD
  const int mb  = xcd * 64 + (j8 >> 3);  // 64 mb's per XCD; 8 consecutive
  const int nb  = j8 & 7;                //   blocks per XCD share one A-panel
  const int m0 = mb * 128, n0 = nb * 128;

  f32x4 acc[4][4] = {};

  // staging geometry: row = tid>>2 (0..63, +64), slot = tid&3 (16B chunks);
  // source chunk swizzled: s ^ ((r>>1)&3) with (r>>1)&3 == (tid>>3)&3
  const int trow = tid >> 2;
  const int tks  = 8 * ((tid & 3) ^ ((tid >> 3) & 3));   // elements
  const size_t axoff0 = (size_t)(m0 + trow) * 512 + tks; // f32 elements in x
  const size_t axoff1 = axoff0 + (size_t)64 * 512;
  const size_t boff0  = (size_t)(n0 + trow) * 512 + tks; // bf16 elements in wt
  const size_t boff1  = boff0 + (size_t)64 * 512;

  // fragment read offset (shorts): row=(lane&15)+16*seg, slot=q^((row>>1)&3)
  const int ra = (lane & 15) * 32 + 8 * ((lane >> 4) ^ ((lane >> 1) & 3));

  float4 sa0, sa1, sa2, sa3;   // staged A (f32), live across COMPUTE

#define ALOAD(k0) { \
    const float* p0 = x + axoff0 + (k0); \
    const float* p1 = x + axoff1 + (k0); \
    sa0 = *(const float4*)p0; sa1 = *(const float4*)(p0 + 4); \
    sa2 = *(const float4*)p1; sa3 = *(const float4*)(p1 + 4); }

#define AWRITE(bf) { \
    uint4 q0, q1; \
    q0.x = cvt_pk_bf16(sa0.x, sa0.y); q0.y = cvt_pk_bf16(sa0.z, sa0.w); \
    q0.z = cvt_pk_bf16(sa1.x, sa1.y); q0.w = cvt_pk_bf16(sa1.z, sa1.w); \
    q1.x = cvt_pk_bf16(sa2.x, sa2.y); q1.y = cvt_pk_bf16(sa2.z, sa2.w); \
    q1.z = cvt_pk_bf16(sa3.x, sa3.y); q1.w = cvt_pk_bf16(sa3.z, sa3.w); \
    char* la = (char*)As + (bf) * 8192 + tid * 16; \
    *(uint4*)la = q0; \
    *(uint4*)(la + 4096) = q1; }

#define BSTAGE(bf, k0) { \
    char* lb = (char*)Bsh + (bf) * 8192 + wave * 1024; \
    gload16(wt + boff0 + (k0), lb); \
    gload16(wt + boff1 + (k0), lb + 4096); }

#define COMPUTE(bf) { \
    const unsigned short* Ab  = &As[bf][0]; \
    const unsigned short* Bb2 = &Bsh[bf][0]; \
    short8 af[4], bfr[4]; \
    _Pragma("unroll") for (int m = 0; m < 4; ++m) \
      af[m] = *(const short8*)(Ab + (wr * 64 + 16 * m) * 32 + ra); \
    _Pragma("unroll") for (int n = 0; n < 4; ++n) \
      bfr[n] = *(const short8*)(Bb2 + (wc * 64 + 16 * n) * 32 + ra); \
    _Pragma("unroll") for (int m = 0; m < 4; ++m) \
      _Pragma("unroll") for (int n = 0; n < 4; ++n) \
        acc[m][n] = __builtin_amdgcn_mfma_f32_16x16x32_bf16(af[m], bfr[n], acc[m][n], 0, 0, 0); }

  // prologue
  ALOAD(0);
  BSTAGE(0, 0);
  AWRITE(0);            // compiler inserts vmcnt wait for sa* here
  __syncthreads();      // drains B gloads + ds_writes

  int buf = 0;
  for (int kt = 0; kt < 15; ++kt) {
    ALOAD((kt + 1) * 32);            // issue next A loads FIRST
    BSTAGE(buf ^ 1, (kt + 1) * 32);  // issue next B gload_lds
    COMPUTE(buf);                    // hides the load latency
    AWRITE(buf ^ 1);                 // cvt + ds_write into idle buffer
    __syncthreads();                 // next tile ready for all waves
    buf ^= 1;
  }
  COMPUTE(buf);

  // ----- Epilogue: pointwise -> cv (bf16x2), + ordered chunk-aggregate -----
  // D layout: col = lane&15, row = (lane>>4)*4 + j  [measured m89]
  const int q     = lane >> 4;
  const int rbase = m0 + wr * 64 + (q << 2);
  const int dbase = nb * 64 + wc * 32 + (lane & 15);

  float CW[2] = {1.f, 1.f};
  float VW[2] = {0.f, 0.f};

#pragma unroll
  for (int m = 0; m < 4; ++m) {
#pragma unroll
    for (int t = 0; t < 2; ++t) {
      float cseg = 1.f, vseg = 0.f;
#pragma unroll
      for (int j = 0; j < 4; ++j) {
        float hid = acc[m][2 * t][j];
        float gat = acc[m][2 * t + 1][j];
        float c  = __builtin_amdgcn_rcpf(1.f + __expf(gat));   // sigmoid(-gate)
        float z  = 1.f - c;                                    // sigmoid(gate)
        float sg = __builtin_amdgcn_rcpf(1.f + __expf(-hid));  // sigmoid(hid)
        float gv = (hid >= 0.f) ? (hid + 0.5f) : sg;
        float v  = z * gv;
        int R = rbase + 16 * m + j;
        int d = dbase + 16 * t;
        cvu[(size_t)R * 512 + d] = cvt_pk_bf16(c, v);
        vseg = fmaf(c, vseg, v);         // ordered fold over j (f32-exact path)
        cseg *= c;
      }
      // ordered combine across q (lane-groups), q ascending = row order
      {
        float Cp = __shfl_xor(cseg, 16);
        float Vp = __shfl_xor(vseg, 16);
        if (q & 1) { vseg = fmaf(cseg, Vp, vseg); cseg = Cp * cseg; }
        else       { vseg = fmaf(Cp, vseg, Vp);   cseg = cseg * Cp; }
        Cp = __shfl_xor(cseg, 32);
        Vp = __shfl_xor(vseg, 32);
        if (q & 2) { vseg = fmaf(cseg, Vp, vseg); cseg = Cp * cseg; }
        else       { vseg = fmaf(Cp, vseg, Vp);   cseg = cseg * Cp; }
      }
      VW[t] = fmaf(cseg, VW[t], vseg);   // fold 16-row segment, m ascending
      CW[t] *= cseg;
    }
  }

  if (lane < 16) {
#pragma unroll
    for (int t = 0; t < 2; ++t) {
      aggC[wr][wc][t][lane] = CW[t];
      aggV[wr][wc][t][lane] = VW[t];
    }
  }
  __syncthreads();
  if (wr == 0 && lane < 16) {
#pragma unroll
    for (int t = 0; t < 2; ++t) {
      float C1 = aggC[1][wc][t][lane];
      float V1 = aggV[1][wc][t][lane];
      int d = nb * 64 + wc * 32 + t * 16 + lane;
      agg[(size_t)mb * 512 + d] = make_float2(CW[t] * C1, fmaf(C1, VW[t], V1));
    }
  }
}

// ---------------------------------------------------------------------------
// Scan kernel (chain fused, r8-proven): each block (b, chunk, d-half) folds
// aggregates 0..chunk-1 for its d, then replays its chunk and writes output.
// 1024 blocks x 256 threads. cv NT-load, out NT-store.
// ---------------------------------------------------------------------------
__global__ void k_scan_out(const uint32_t* __restrict__ cvu,
                           const float* __restrict__ prev,
                           const float2* __restrict__ agg,
                           float* __restrict__ out) {
  const int bid   = blockIdx.x;          // 1024 = 8 b * 64 chunk * 2 dh
  const int dh    = bid & 1;
  const int chunk = (bid >> 1) & 63;
  const int b     = bid >> 7;
  const int d     = dh * 256 + threadIdx.x;

  // h0 = g(prev_hidden)
  float p = prev[b * 512 + d];
  float h = (p >= 0.f) ? (p + 0.5f) : (1.f / (1.f + __expf(-p)));

  // chain: fold chunk aggregates 0..chunk-1 (loads independent, fma serial)
  const float2* ag = agg + (size_t)(b * NC) * 512 + d;
#pragma unroll 4
  for (int k = 0; k < chunk; ++k) {
    float2 a = ag[(size_t)k * 512];
    h = fmaf(a.x, h, a.y);
  }

  // replay this chunk with exact incoming h
  const size_t base = ((size_t)(b * Ss + chunk * CL)) * 512 + d;
#pragma unroll 8
  for (int i = 0; i < CL; ++i) {
    uint32_t t = __builtin_nontemporal_load(cvu + base + (size_t)i * 512);
    float c = __uint_as_float(t << 16);
    float v = __uint_as_float(t & 0xFFFF0000u);
    h = fmaf(c, h, v);
    __builtin_nontemporal_store(h, out + base + (size_t)i * 512);
  }
}

// ---------------------------------------------------------------------------
extern "C" void kernel_launch(void* const* d_in, const int* in_sizes, int n_in,
                              void* d_out, int out_size, void* d_ws, size_t ws_size,
                              hipStream_t stream) {
  if (ws_size < WS_NEED) return;  // need ~131 MiB scratch

  const float* x    = (const float*)d_in[0];
  const float* prev = (const float*)d_in[1];
  const float* W    = (const float*)d_in[2];
  float* out = (float*)d_out;
  char* ws = (char*)d_ws;

  uint32_t*       cvu = (uint32_t*)(ws + CV_OFF);
  unsigned short* wt  = (unsigned short*)(ws + WT_OFF);
  float2*         agg = (float2*)(ws + AG_OFF);

  k_prep_wt<<<dim3(512), dim3(256), 0, stream>>>(W, wt);
  k_gemm<<<dim3(4096), dim3(256), 0, stream>>>(x, wt, cvu, agg);
  k_scan_out<<<dim3(1024), dim3(256), 0, stream>>>(cvu, prev, agg, out);
}

// Round 11
// 349.392 us; speedup vs baseline: 1.1358x; 1.1358x over previous
//
#include <hip/hip_runtime.h>
#include <stdint.h>

// Problem constants (B=8, S=8192, D_IN=512, D=512)
#define Bb   8
#define Ss   8192
#define DIN  512
#define Dd   512
#define M_TOT (Bb * Ss)      // 65536 rows
#define NC   64              // chunks along S
#define CL   128             // chunk length (NC*CL == Ss) == GEMM M-tile

// ws layout (bytes)
static const size_t CV_OFF  = 0;                          // bf16x2 [65536][512] = 128 MiB
static const size_t XS_OFF  = 134217728ull;               // bf16 [65536][512]  =  64 MiB
static const size_t WT_OFF  = XS_OFF + 67108864ull;       // bf16 [1024][512]   =   1 MiB
static const size_t AG_OFF  = WT_OFF + 1048576ull;        // float2[512][512]   =   2 MiB
static const size_t WS_NEED = AG_OFF + 2097152ull;        // ~195 MiB total

typedef short  short8 __attribute__((ext_vector_type(8)));
typedef float  f32x4  __attribute__((ext_vector_type(4)));

__device__ __forceinline__ unsigned short bf16_rne(float f) {
  uint32_t u = __float_as_uint(f);
  u += 0x7fffu + ((u >> 16) & 1u);
  return (unsigned short)(u >> 16);
}

__device__ __forceinline__ void gload16(const unsigned short* g, void* l) {
  __builtin_amdgcn_global_load_lds(
      (const __attribute__((address_space(1))) uint32_t*)g,
      (__attribute__((address_space(3))) uint32_t*)l, 16, 0, 0);
}

__device__ __forceinline__ uint32_t cvt_pk_bf16(float lo, float hi) {
  uint32_t r;
  asm("v_cvt_pk_bf16_f32 %0, %1, %2" : "=v"(r) : "v"(lo), "v"(hi));
  return r;
}

// ---------------------------------------------------------------------------
// Pre-pass (merged, r8-proven): blocks [0,4096): x f32 -> xs bf16 [row][512]
//                               blocks [4096,4608): W -> wt bf16 [1024 n'][512]
//   n' interleave (16-granular): hidden col d -> n'=32*(d>>4)+(d&15),
//                                gate   col d -> n'=32*(d>>4)+16+(d&15)
// ---------------------------------------------------------------------------
__global__ void k_prep(const float* __restrict__ x, const float* __restrict__ W,
                       unsigned short* __restrict__ xs, unsigned short* __restrict__ wt) {
  const int bx = blockIdx.x;
  if (bx < 4096) {
    const size_t n4 = (size_t)M_TOT * DIN / 4;     // 8M float4
    for (size_t i = (size_t)bx * 256 + threadIdx.x; i < n4; i += (size_t)4096 * 256) {
      float4 v = ((const float4*)x)[i];
      size_t e = i * 4;
      size_t r = e >> 9;
      int    k = (int)(e & 511);
      ushort4 hi;
      unsigned short* hp = (unsigned short*)&hi;
      hp[0] = bf16_rne(v.x); hp[1] = bf16_rne(v.y);
      hp[2] = bf16_rne(v.z); hp[3] = bf16_rne(v.w);
      *(ushort4*)(xs + r * 512 + k) = hi;
    }
  } else {
    // coalesced W reads; scattered writes land in the 1 MiB L2-resident wt
    const int t0 = (bx - 4096) * 256 + threadIdx.x;   // 131072 threads
    for (int i = t0; i < 512 * 1024; i += 131072) {
      int k = i >> 10;       // W row
      int j = i & 1023;      // W col
      float w = W[i];
      int n = (j < 512) ? (32 * (j >> 4) + (j & 15))
                        : (32 * ((j - 512) >> 4) + 16 + ((j - 512) & 15));
      wt[n * 512 + k] = bf16_rne(w);
    }
  }
}

// ---------------------------------------------------------------------------
// GEMM (r8 structure, 122 us proven + r10-validated fast epilogue):
// (65536 x 512) * (512 x 1024) -> pointwise -> cv bf16x2 + chunk aggregates.
// 128x128 tile, BK=32, 4 waves (2x2 of 64x64), 16x16x32 bf16 MFMA.
// 2-phase double-buffered: STAGE(next) -> COMPUTE(cur) -> one barrier.
// A and B both staged via global_load_lds from bf16 (no reg round-trip —
// r10 showed reg-staging A stalls at the post-COMPUTE vmcnt wait, -66 us).
// LDS swizzle (rule 21, conflicts=0 verified r4): linear gload_lds dest;
// SOURCE chunk = s^((r>>1)&3); READ slot = q^((r>>1)&3).
// XCD-aware mapping: 8 nb-blocks sharing an A-panel land on the SAME XCD.
// ---------------------------------------------------------------------------
__global__ void __launch_bounds__(256) k_gemm(const unsigned short* __restrict__ xs,
                                              const unsigned short* __restrict__ wt,
                                              uint32_t* __restrict__ cvu,
                                              float2* __restrict__ agg) {
  __shared__ __align__(16) unsigned short As[2][128 * 32];
  __shared__ __align__(16) unsigned short Bsh[2][128 * 32];
  __shared__ float aggC[2][2][2][16];   // [wr][wc][t][lane&15]
  __shared__ float aggV[2][2][2][16];

  const int tid  = threadIdx.x;
  const int lane = tid & 63;
  const int wave = tid >> 6;
  const int wr = wave >> 1, wc = wave & 1;

  // XCD-aware tile mapping (round-robin bid%8 -> XCD assumed)
  const int bid = blockIdx.x;
  const int xcd = bid & 7;
  const int j8  = bid >> 3;              // 0..511, sequential per XCD
  const int mb  = xcd * 64 + (j8 >> 3);  // 64 mb's per XCD; 8 consecutive
  const int nb  = j8 & 7;                //   blocks per XCD share one A-panel
  const int m0 = mb * 128, n0 = nb * 128;

  f32x4 acc[4][4] = {};

  // staging: LDS linear (row = tid>>2, slot = tid&3); source chunk swizzled
  const int trow = tid >> 2;
  const int tks  = 8 * ((tid & 3) ^ ((tid >> 3) & 3));   // shorts
  const size_t aoff0 = (size_t)(m0 + trow) * 512 + tks;
  const size_t aoff1 = aoff0 + (size_t)64 * 512;
  const size_t boff0 = (size_t)(n0 + trow) * 512 + tks;
  const size_t boff1 = boff0 + (size_t)64 * 512;

  // fragment read offset (shorts): row=(lane&15)+16*seg, slot=q^((row>>1)&3)
  const int ra = (lane & 15) * 32 + 8 * ((lane >> 4) ^ ((lane >> 1) & 3));

#define STAGE(bf, k0) { \
    char* la = (char*)As  + (bf) * 8192 + wave * 1024; \
    char* lb = (char*)Bsh + (bf) * 8192 + wave * 1024; \
    gload16(xs + aoff0 + (k0), la); \
    gload16(xs + aoff1 + (k0), la + 4096); \
    gload16(wt + boff0 + (k0), lb); \
    gload16(wt + boff1 + (k0), lb + 4096); }

#define COMPUTE(bf) { \
    const unsigned short* Ab  = &As[bf][0]; \
    const unsigned short* Bb2 = &Bsh[bf][0]; \
    short8 af[4], bfr[4]; \
    _Pragma("unroll") for (int m = 0; m < 4; ++m) \
      af[m] = *(const short8*)(Ab + (wr * 64 + 16 * m) * 32 + ra); \
    _Pragma("unroll") for (int n = 0; n < 4; ++n) \
      bfr[n] = *(const short8*)(Bb2 + (wc * 64 + 16 * n) * 32 + ra); \
    _Pragma("unroll") for (int m = 0; m < 4; ++m) \
      _Pragma("unroll") for (int n = 0; n < 4; ++n) \
        acc[m][n] = __builtin_amdgcn_mfma_f32_16x16x32_bf16(af[m], bfr[n], acc[m][n], 0, 0, 0); }

  STAGE(0, 0);
  __syncthreads();
  int buf = 0;
  for (int kt = 0; kt < 15; ++kt) {
    STAGE(buf ^ 1, (kt + 1) * 32);   // issue next-tile loads FIRST
    COMPUTE(buf);                     // ds_read + MFMA hide the load latency
    __syncthreads();                  // implicit vmcnt(0): next tile ready
    buf ^= 1;
  }
  COMPUTE(buf);

  // ----- Epilogue: pointwise -> cv (bf16x2), + ordered chunk-aggregate -----
  // Fast ops validated r10 (rcpf rel-err 1e-6 << bf16 ulp; cvt_pk is RNE).
  // D layout: col = lane&15, row = (lane>>4)*4 + j  [measured m89]
  const int q     = lane >> 4;
  const int rbase = m0 + wr * 64 + (q << 2);
  const int dbase = nb * 64 + wc * 32 + (lane & 15);

  float CW[2] = {1.f, 1.f};
  float VW[2] = {0.f, 0.f};

#pragma unroll
  for (int m = 0; m < 4; ++m) {
#pragma unroll
    for (int t = 0; t < 2; ++t) {
      float cseg = 1.f, vseg = 0.f;
#pragma unroll
      for (int j = 0; j < 4; ++j) {
        float hid = acc[m][2 * t][j];
        float gat = acc[m][2 * t + 1][j];
        float c  = __builtin_amdgcn_rcpf(1.f + __expf(gat));   // sigmoid(-gate)
        float z  = 1.f - c;                                    // sigmoid(gate)
        float sg = __builtin_amdgcn_rcpf(1.f + __expf(-hid));  // sigmoid(hid)
        float gv = (hid >= 0.f) ? (hid + 0.5f) : sg;
        float v  = z * gv;
        int R = rbase + 16 * m + j;
        int d = dbase + 16 * t;
        cvu[(size_t)R * 512 + d] = cvt_pk_bf16(c, v);
        vseg = fmaf(c, vseg, v);         // ordered fold over j (f32-exact path)
        cseg *= c;
      }
      // ordered combine across q (lane-groups), q ascending = row order
      {
        float Cp = __shfl_xor(cseg, 16);
        float Vp = __shfl_xor(vseg, 16);
        if (q & 1) { vseg = fmaf(cseg, Vp, vseg); cseg = Cp * cseg; }
        else       { vseg = fmaf(Cp, vseg, Vp);   cseg = cseg * Cp; }
        Cp = __shfl_xor(cseg, 32);
        Vp = __shfl_xor(vseg, 32);
        if (q & 2) { vseg = fmaf(cseg, Vp, vseg); cseg = Cp * cseg; }
        else       { vseg = fmaf(Cp, vseg, Vp);   cseg = cseg * Cp; }
      }
      VW[t] = fmaf(cseg, VW[t], vseg);   // fold 16-row segment, m ascending
      CW[t] *= cseg;
    }
  }

  if (lane < 16) {
#pragma unroll
    for (int t = 0; t < 2; ++t) {
      aggC[wr][wc][t][lane] = CW[t];
      aggV[wr][wc][t][lane] = VW[t];
    }
  }
  __syncthreads();
  if (wr == 0 && lane < 16) {
#pragma unroll
    for (int t = 0; t < 2; ++t) {
      float C1 = aggC[1][wc][t][lane];
      float V1 = aggV[1][wc][t][lane];
      int d = nb * 64 + wc * 32 + t * 16 + lane;
      agg[(size_t)mb * 512 + d] = make_float2(CW[t] * C1, fmaf(C1, VW[t], V1));
    }
  }
}

// ---------------------------------------------------------------------------
// Scan kernel (chain fused, r8-proven): each block (b, chunk, d-half) folds
// aggregates 0..chunk-1 for its d, then replays its chunk and writes output.
// 1024 blocks x 256 threads. cv NT-load, out NT-store.
// ---------------------------------------------------------------------------
__global__ void k_scan_out(const uint32_t* __restrict__ cvu,
                           const float* __restrict__ prev,
                           const float2* __restrict__ agg,
                           float* __restrict__ out) {
  const int bid   = blockIdx.x;          // 1024 = 8 b * 64 chunk * 2 dh
  const int dh    = bid & 1;
  const int chunk = (bid >> 1) & 63;
  const int b     = bid >> 7;
  const int d     = dh * 256 + threadIdx.x;

  // h0 = g(prev_hidden)
  float p = prev[b * 512 + d];
  float h = (p >= 0.f) ? (p + 0.5f) : (1.f / (1.f + __expf(-p)));

  // chain: fold chunk aggregates 0..chunk-1 (loads independent, fma serial)
  const float2* ag = agg + (size_t)(b * NC) * 512 + d;
#pragma unroll 4
  for (int k = 0; k < chunk; ++k) {
    float2 a = ag[(size_t)k * 512];
    h = fmaf(a.x, h, a.y);
  }

  // replay this chunk with exact incoming h
  const size_t base = ((size_t)(b * Ss + chunk * CL)) * 512 + d;
#pragma unroll 8
  for (int i = 0; i < CL; ++i) {
    uint32_t t = __builtin_nontemporal_load(cvu + base + (size_t)i * 512);
    float c = __uint_as_float(t << 16);
    float v = __uint_as_float(t & 0xFFFF0000u);
    h = fmaf(c, h, v);
    __builtin_nontemporal_store(h, out + base + (size_t)i * 512);
  }
}

// ---------------------------------------------------------------------------
extern "C" void kernel_launch(void* const* d_in, const int* in_sizes, int n_in,
                              void* d_out, int out_size, void* d_ws, size_t ws_size,
                              hipStream_t stream) {
  if (ws_size < WS_NEED) return;  // need ~195 MiB scratch

  const float* x    = (const float*)d_in[0];
  const float* prev = (const float*)d_in[1];
  const float* W    = (const float*)d_in[2];
  float* out = (float*)d_out;
  char* ws = (char*)d_ws;

  uint32_t*       cvu = (uint32_t*)(ws + CV_OFF);
  unsigned short* xs  = (unsigned short*)(ws + XS_OFF);
  unsigned short* wt  = (unsigned short*)(ws + WT_OFF);
  float2*         agg = (float2*)(ws + AG_OFF);

  k_prep<<<dim3(4608), dim3(256), 0, stream>>>(x, W, xs, wt);
  k_gemm<<<dim3(4096), dim3(256), 0, stream>>>(xs, wt, cvu, agg);
  k_scan_out<<<dim3(1024), dim3(256), 0, stream>>>(cvu, prev, agg, out);
}